// Round 1
// baseline (447.798 us; speedup 1.0000x reference)
//
#include <hip/hip_runtime.h>
#include <stdint.h>

#define B_ROWS 8192
#define DH     1024
#define KTOT   2048   // D_IN + D_H

using short8 = __attribute__((ext_vector_type(8))) short;  // 8 bf16 (4 VGPRs)
using f32x4  = __attribute__((ext_vector_type(4))) float;  // MFMA accumulator

// f32 -> bf16 round-to-nearest-even
__device__ __forceinline__ short bfr(float f) {
    uint32_t u = __float_as_uint(f);
    u = (u + 0x7FFFu + ((u >> 16) & 1u)) >> 16;
    return (short)u;
}

__device__ __forceinline__ float sigm(float x) {
    x = fminf(fmaxf(x, -20.f), 20.f);
    return 1.f / (1.f + __expf(-x));
}
__device__ __forceinline__ float tanh_(float x) {
    x = fminf(fmaxf(x, -10.f), 10.f);
    float e = __expf(2.f * x);
    return (e - 1.f) / (e + 1.f);
}

// async global->LDS, 16B per lane (HW: wave-uniform LDS base + lane*16)
__device__ __forceinline__ void gl16(const void* g, void* l) {
    __builtin_amdgcn_global_load_lds(
        (const __attribute__((address_space(1))) uint32_t*)(uintptr_t)g,
        (__attribute__((address_space(3))) uint32_t*)(uint32_t)(uintptr_t)l,
        16, 0, 0);
}

// A[8192][2048] bf16 = [x | h]
__global__ __launch_bounds__(256) void build_A(const float* __restrict__ x,
                                               const float* __restrict__ h,
                                               short* __restrict__ A) {
    int t   = blockIdx.x * 256 + threadIdx.x;   // 8-element group index
    int row = t >> 8;                           // 2048/8 = 256 groups per row
    int col = (t & 255) * 8;
    const float* src = (col < 1024) ? (x + (size_t)row * 1024 + col)
                                    : (h + (size_t)row * 1024 + (col - 1024));
    float4 f0 = ((const float4*)src)[0];
    float4 f1 = ((const float4*)src)[1];
    short8 o;
    o[0] = bfr(f0.x); o[1] = bfr(f0.y); o[2] = bfr(f0.z); o[3] = bfr(f0.w);
    o[4] = bfr(f1.x); o[5] = bfr(f1.y); o[6] = bfr(f1.z); o[7] = bfr(f1.w);
    *(short8*)(A + (size_t)row * KTOT + col) = o;
}

// Wcat[4096][2048] bf16, gate-major rows: gate g row n = [Wg[n] | Ug[n]]
__global__ __launch_bounds__(256) void build_W(
        const float* __restrict__ Wi, const float* __restrict__ Ui,
        const float* __restrict__ Wf, const float* __restrict__ Uf,
        const float* __restrict__ Wo, const float* __restrict__ Uo,
        const float* __restrict__ Wc, const float* __restrict__ Uc,
        short* __restrict__ Wcat) {
    int row  = blockIdx.x;          // 0..4095 (one row per block)
    int col  = threadIdx.x * 8;     // 0..2047
    int gate = row >> 10;
    int n    = row & 1023;
    const float* Wg = (gate == 0) ? Wi : (gate == 1) ? Wf : (gate == 2) ? Wo : Wc;
    const float* Ug = (gate == 0) ? Ui : (gate == 1) ? Uf : (gate == 2) ? Uo : Uc;
    const float* src = (col < 1024) ? (Wg + (size_t)n * 1024 + col)
                                    : (Ug + (size_t)n * 1024 + (col - 1024));
    float4 f0 = ((const float4*)src)[0];
    float4 f1 = ((const float4*)src)[1];
    short8 o;
    o[0] = bfr(f0.x); o[1] = bfr(f0.y); o[2] = bfr(f0.z); o[3] = bfr(f0.w);
    o[4] = bfr(f1.x); o[5] = bfr(f1.y); o[6] = bfr(f1.z); o[7] = bfr(f1.w);
    *(short8*)(Wcat + (size_t)row * KTOT + col) = o;
}

// Fused 4-gate GEMM + LSTM epilogue.
// 128x128 tile over [B, H]; 4 waves in 2x2, each wave 64x64 (4x4 of 16x16).
// Per block: 4 sequential K=2048 passes in gate order {i, c~, f, o}, one
// 64-reg stash folds the whole cell update (avoids a 128 MiB gates buffer).
__global__ __launch_bounds__(256, 2) void lstm_main(
        const short* __restrict__ A, const short* __restrict__ Wcat,
        const float* __restrict__ bi, const float* __restrict__ bff,
        const float* __restrict__ bo, const float* __restrict__ bc,
        const float* __restrict__ cin, float* __restrict__ out) {
    __shared__ __align__(16) short At[128 * 32];
    __shared__ __align__(16) short Bt[128 * 32];

    const int tid  = threadIdx.x;
    const int lane = tid & 63;
    const int wave = tid >> 6;
    const int wr   = wave >> 1, wc = wave & 1;
    const int l15  = lane & 15, l16 = lane >> 4;
    const int col0 = blockIdx.x * 128;   // over H
    const int row0 = blockIdx.y * 128;   // over B

    // staging: thread covers 16B at tile-linear byte offset tid*16 (+4096)
    const int srow = tid >> 2;           // 0..63
    const int scg  = (tid & 3) * 8;      // k offset in elements
    const short* gA0 = A + (size_t)(row0 + srow) * KTOT + scg;
    const short* gA1 = gA0 + (size_t)64 * KTOT;
    short* lA0 = At + tid * 8;
    short* lA1 = At + tid * 8 + 2048;
    short* lB0 = Bt + tid * 8;
    short* lB1 = Bt + tid * 8 + 2048;

    // fragment offsets (shorts): row = (wr|wc)*64 + mi*16 + l15, k = l16*8
    const int aoff = (wr * 64 + l15) * 32 + l16 * 8;
    const int boff = (wc * 64 + l15) * 32 + l16 * 8;

    f32x4 acc[4][4];
    float st[4][4][4];
    #pragma unroll
    for (int mi = 0; mi < 4; ++mi)
        #pragma unroll
        for (int ni = 0; ni < 4; ++ni)
            acc[mi][ni] = f32x4{0.f, 0.f, 0.f, 0.f};

    const int   gateof[4] = {0, 3, 1, 2};          // i, c~, f, o
    const float* biasp[4] = {bi, bc, bff, bo};

    #pragma unroll
    for (int pass = 0; pass < 4; ++pass) {
        const short* pb0 = Wcat + (size_t)(gateof[pass] * 1024 + col0 + srow) * KTOT + scg;
        const short* pb1 = pb0 + (size_t)64 * KTOT;
        const short* pa0 = gA0;
        const short* pa1 = gA1;

        for (int kt = 0; kt < KTOT / 32; ++kt) {
            gl16(pa0, lA0); gl16(pa1, lA1);
            gl16(pb0, lB0); gl16(pb1, lB1);
            pa0 += 32; pa1 += 32; pb0 += 32; pb1 += 32;
            __syncthreads();               // drains vmcnt -> tiles visible
            short8 af[4], bf8[4];
            #pragma unroll
            for (int mi = 0; mi < 4; ++mi)
                af[mi] = *(const short8*)(At + aoff + mi * 16 * 32);
            #pragma unroll
            for (int ni = 0; ni < 4; ++ni)
                bf8[ni] = *(const short8*)(Bt + boff + ni * 16 * 32);
            #pragma unroll
            for (int mi = 0; mi < 4; ++mi)
                #pragma unroll
                for (int ni = 0; ni < 4; ++ni)
                    acc[mi][ni] = __builtin_amdgcn_mfma_f32_16x16x32_bf16(
                        af[mi], bf8[ni], acc[mi][ni], 0, 0, 0);
            __syncthreads();               // all reads done before re-stage
        }

        const float* bp = biasp[pass];
        #pragma unroll
        for (int ni = 0; ni < 4; ++ni) {
            const int col = col0 + wc * 64 + ni * 16 + l15;
            const float bv = bp[col];
            #pragma unroll
            for (int mi = 0; mi < 4; ++mi) {
                const int rbase = row0 + wr * 64 + mi * 16 + l16 * 4;
                #pragma unroll
                for (int r = 0; r < 4; ++r) {
                    float g = acc[mi][ni][r] + bv;
                    if (pass == 0) {                       // i
                        st[mi][ni][r] = sigm(g);
                    } else if (pass == 1) {                // c~
                        st[mi][ni][r] *= tanh_(g);
                    } else if (pass == 2) {                // f -> new_c
                        const size_t row = (size_t)(rbase + r);
                        float cv = cin[row * DH + col];
                        float nc = sigm(g) * cv + st[mi][ni][r];
                        out[(size_t)B_ROWS * DH + row * DH + col] = nc;
                        st[mi][ni][r] = tanh_(nc);
                    } else {                               // o -> new_h
                        const size_t row = (size_t)(rbase + r);
                        out[row * DH + col] = sigm(g) * st[mi][ni][r];
                    }
                    acc[mi][ni][r] = 0.f;
                }
            }
        }
    }
}

extern "C" void kernel_launch(void* const* d_in, const int* in_sizes, int n_in,
                              void* d_out, int out_size, void* d_ws, size_t ws_size,
                              hipStream_t stream) {
    (void)in_sizes; (void)n_in; (void)out_size; (void)ws_size;
    const float* x  = (const float*)d_in[0];
    const float* h  = (const float*)d_in[1];
    const float* c  = (const float*)d_in[2];
    const float* Wi = (const float*)d_in[3];
    const float* bi = (const float*)d_in[4];
    const float* Ui = (const float*)d_in[5];
    const float* Wf = (const float*)d_in[6];
    const float* bf = (const float*)d_in[7];
    const float* Uf = (const float*)d_in[8];
    const float* Wo = (const float*)d_in[9];
    const float* bo = (const float*)d_in[10];
    const float* Uo = (const float*)d_in[11];
    const float* Wc = (const float*)d_in[12];
    const float* bc = (const float*)d_in[13];
    const float* Uc = (const float*)d_in[14];
    float* out = (float*)d_out;

    short* A    = (short*)d_ws;                              // 32 MiB
    short* Wcat = A + (size_t)B_ROWS * KTOT;                 // +16 MiB

    hipLaunchKernelGGL(build_A, dim3(8192), dim3(256), 0, stream, x, h, A);
    hipLaunchKernelGGL(build_W, dim3(4096), dim3(256), 0, stream,
                       Wi, Ui, Wf, Uf, Wo, Uo, Wc, Uc, Wcat);
    hipLaunchKernelGGL(lstm_main, dim3(8, 64), dim3(256), 0, stream,
                       A, Wcat, bi, bf, bo, bc, c, out);
}

// Round 2
// 385.652 us; speedup vs baseline: 1.1611x; 1.1611x over previous
//
#include <hip/hip_runtime.h>
#include <stdint.h>

#define B_ROWS 8192
#define DH     1024
#define KTOT   2048   // D_IN + D_H
#define GC     4096   // 4 * DH gate-columns

using short8 = __attribute__((ext_vector_type(8))) short;  // 8 bf16 (4 VGPRs)
using f32x4  = __attribute__((ext_vector_type(4))) float;  // MFMA accumulator

// f32 -> bf16 round-to-nearest-even
__device__ __forceinline__ short bfr(float f) {
    uint32_t u = __float_as_uint(f);
    u = (u + 0x7FFFu + ((u >> 16) & 1u)) >> 16;
    return (short)u;
}

__device__ __forceinline__ float sigm(float x) {
    x = fminf(fmaxf(x, -20.f), 20.f);
    return 1.f / (1.f + __expf(-x));
}
__device__ __forceinline__ float tanh_(float x) {
    x = fminf(fmaxf(x, -10.f), 10.f);
    float e = __expf(2.f * x);
    return (e - 1.f) / (e + 1.f);
}

// async global->LDS, 16B per lane (HW: wave-uniform LDS base + lane*16)
__device__ __forceinline__ void gl16(const void* g, void* l) {
    __builtin_amdgcn_global_load_lds(
        (const __attribute__((address_space(1))) uint32_t*)(uintptr_t)g,
        (__attribute__((address_space(3))) uint32_t*)(uint32_t)(uintptr_t)l,
        16, 0, 0);
}

// A[8192][2048] bf16 = [x | h]   (batch-major, K contiguous)
__global__ __launch_bounds__(256) void build_A(const float* __restrict__ x,
                                               const float* __restrict__ h,
                                               short* __restrict__ A) {
    int t   = blockIdx.x * 256 + threadIdx.x;   // 8-element group index
    int row = t >> 8;                           // 2048/8 = 256 groups per row
    int col = (t & 255) * 8;
    const float* src = (col < 1024) ? (x + (size_t)row * 1024 + col)
                                    : (h + (size_t)row * 1024 + (col - 1024));
    float4 f0 = ((const float4*)src)[0];
    float4 f1 = ((const float4*)src)[1];
    short8 o;
    o[0] = bfr(f0.x); o[1] = bfr(f0.y); o[2] = bfr(f0.z); o[3] = bfr(f0.w);
    o[4] = bfr(f1.x); o[5] = bfr(f1.y); o[6] = bfr(f1.z); o[7] = bfr(f1.w);
    *(short8*)(A + (size_t)row * KTOT + col) = o;
}

// Wrow[4096][2048] bf16, GATE-INTERLEAVED rows: row r = 4*hcol + gate,
// gate order {i,f,o,c}:  Wrow[r] = [Wg[hcol] | Ug[hcol]]
__global__ __launch_bounds__(256) void build_W(
        const float* __restrict__ Wi, const float* __restrict__ Ui,
        const float* __restrict__ Wf, const float* __restrict__ Uf,
        const float* __restrict__ Wo, const float* __restrict__ Uo,
        const float* __restrict__ Wc, const float* __restrict__ Uc,
        short* __restrict__ Wrow) {
    int row  = blockIdx.x;          // 0..4095
    int col  = threadIdx.x * 8;     // 0..2047
    int n    = row >> 2;            // hcol
    int gate = row & 3;             // 0=i,1=f,2=o,3=c~
    const float* Wg = (gate == 0) ? Wi : (gate == 1) ? Wf : (gate == 2) ? Wo : Wc;
    const float* Ug = (gate == 0) ? Ui : (gate == 1) ? Uf : (gate == 2) ? Uo : Uc;
    const float* src = (col < 1024) ? (Wg + (size_t)n * 1024 + col)
                                    : (Ug + (size_t)n * 1024 + (col - 1024));
    float4 f0 = ((const float4*)src)[0];
    float4 f1 = ((const float4*)src)[1];
    short8 o;
    o[0] = bfr(f0.x); o[1] = bfr(f0.y); o[2] = bfr(f0.z); o[3] = bfr(f0.w);
    o[4] = bfr(f1.x); o[5] = bfr(f1.y); o[6] = bfr(f1.z); o[7] = bfr(f1.w);
    *(short8*)(Wrow + (size_t)row * KTOT + col) = o;
}

// gatesT = Wrow (M=4096 gatecols) x A^T (N=8192 batch), K=2048.
// MFMA C-layout: row=(lane>>4)*4+reg -> gatecol, col=lane&15 -> batchrow.
// With gate-interleaved rows, reg 0..3 = gates {i,f,o,c~} of ONE (hcol,row):
// the LSTM epilogue is fully lane-local. Single K pass, no stash.
__global__ __launch_bounds__(256, 4) void lstm_main(
        const short* __restrict__ A, const short* __restrict__ Wrow,
        const float* __restrict__ bi, const float* __restrict__ bff,
        const float* __restrict__ bo, const float* __restrict__ bc,
        const float* __restrict__ cin, float* __restrict__ out) {
    __shared__ __align__(16) short Wt[128 * 32];   // M-tile (gatecols)
    __shared__ __align__(16) short Bt[128 * 32];   // N-tile (batch rows)

    const int tid  = threadIdx.x;
    const int lane = tid & 63;
    const int wave = tid >> 6;
    const int wr   = wave >> 1, wc = wave & 1;     // wave 2x2: M x N
    const int l15  = lane & 15, l16 = lane >> 4;

    // bijective XCD swizzle (2048 % 8 == 0)
    const int nwg = gridDim.x;                     // 2048
    const int bid = blockIdx.x;
    const int swz = (bid & 7) * (nwg >> 3) + (bid >> 3);
    const int mtile = swz & 31;                    // 32 gatecol tiles
    const int ntile = swz >> 5;                    // 64 batch tiles
    const int m0 = mtile * 128;                    // gatecol base
    const int n0 = ntile * 128;                    // batch base

    // staging: thread covers 16B at tile-linear byte offset tid*16 (+4096)
    const int srow = tid >> 2;                     // 0..63
    const int scg  = (tid & 3) * 8;                // k offset in elements
    const short* pw0 = Wrow + (size_t)(m0 + srow) * KTOT + scg;
    const short* pw1 = pw0 + (size_t)64 * KTOT;
    const short* pa0 = A + (size_t)(n0 + srow) * KTOT + scg;
    const short* pa1 = pa0 + (size_t)64 * KTOT;
    short* lW0 = Wt + tid * 8;
    short* lW1 = Wt + tid * 8 + 2048;
    short* lB0 = Bt + tid * 8;
    short* lB1 = Bt + tid * 8 + 2048;

    const int aoff = (wr * 64 + l15) * 32 + l16 * 8;   // Wrow fragment
    const int boff = (wc * 64 + l15) * 32 + l16 * 8;   // A fragment

    f32x4 acc[4][4];
    #pragma unroll
    for (int mi = 0; mi < 4; ++mi)
        #pragma unroll
        for (int ni = 0; ni < 4; ++ni)
            acc[mi][ni] = f32x4{0.f, 0.f, 0.f, 0.f};

    for (int kt = 0; kt < KTOT / 32; ++kt) {
        gl16(pw0, lW0); gl16(pw1, lW1);
        gl16(pa0, lB0); gl16(pa1, lB1);
        pw0 += 32; pw1 += 32; pa0 += 32; pa1 += 32;
        __syncthreads();               // drains vmcnt -> tiles visible
        short8 wf[4], af[4];
        #pragma unroll
        for (int mi = 0; mi < 4; ++mi)
            wf[mi] = *(const short8*)(Wt + aoff + mi * 16 * 32);
        #pragma unroll
        for (int ni = 0; ni < 4; ++ni)
            af[ni] = *(const short8*)(Bt + boff + ni * 16 * 32);
        #pragma unroll
        for (int mi = 0; mi < 4; ++mi)
            #pragma unroll
            for (int ni = 0; ni < 4; ++ni)
                acc[mi][ni] = __builtin_amdgcn_mfma_f32_16x16x32_bf16(
                    wf[mi], af[ni], acc[mi][ni], 0, 0, 0);
        __syncthreads();               // all reads done before re-stage
    }

    // epilogue: reg r = gate r of (hcol, batchrow); all lane-local
    const int hbase = (m0 >> 2) + wr * 16;
    #pragma unroll
    for (int mi = 0; mi < 4; ++mi) {
        const int hcol = hbase + mi * 4 + l16;
        const float bvi = bi[hcol];
        const float bvf = bff[hcol];
        const float bvo = bo[hcol];
        const float bvc = bc[hcol];
        #pragma unroll
        for (int ni = 0; ni < 4; ++ni) {
            const size_t brow = (size_t)(n0 + wc * 64 + ni * 16 + l15);
            const float cv = cin[brow * DH + hcol];
            const float gi = acc[mi][ni][0] + bvi;
            const float gf = acc[mi][ni][1] + bvf;
            const float go = acc[mi][ni][2] + bvo;
            const float gc = acc[mi][ni][3] + bvc;
            const float nc = sigm(gf) * cv + sigm(gi) * tanh_(gc);
            const float nh = sigm(go) * tanh_(nc);
            out[brow * DH + hcol] = nh;
            out[(size_t)B_ROWS * DH + brow * DH + hcol] = nc;
        }
    }
}

extern "C" void kernel_launch(void* const* d_in, const int* in_sizes, int n_in,
                              void* d_out, int out_size, void* d_ws, size_t ws_size,
                              hipStream_t stream) {
    (void)in_sizes; (void)n_in; (void)out_size; (void)ws_size;
    const float* x  = (const float*)d_in[0];
    const float* h  = (const float*)d_in[1];
    const float* c  = (const float*)d_in[2];
    const float* Wi = (const float*)d_in[3];
    const float* bi = (const float*)d_in[4];
    const float* Ui = (const float*)d_in[5];
    const float* Wf = (const float*)d_in[6];
    const float* bf = (const float*)d_in[7];
    const float* Uf = (const float*)d_in[8];
    const float* Wo = (const float*)d_in[9];
    const float* bo = (const float*)d_in[10];
    const float* Uo = (const float*)d_in[11];
    const float* Wc = (const float*)d_in[12];
    const float* bc = (const float*)d_in[13];
    const float* Uc = (const float*)d_in[14];
    float* out = (float*)d_out;

    short* A    = (short*)d_ws;                              // 32 MiB
    short* Wrow = A + (size_t)B_ROWS * KTOT;                 // +16 MiB

    hipLaunchKernelGGL(build_A, dim3(8192), dim3(256), 0, stream, x, h, A);
    hipLaunchKernelGGL(build_W, dim3(4096), dim3(256), 0, stream,
                       Wi, Ui, Wf, Uf, Wo, Uo, Wc, Uc, Wrow);
    hipLaunchKernelGGL(lstm_main, dim3(2048), dim3(256), 0, stream,
                       A, Wrow, bi, bf, bo, bc, c, out);
}

// Round 5
// 364.111 us; speedup vs baseline: 1.2298x; 1.0592x over previous
//
#include <hip/hip_runtime.h>
#include <stdint.h>

#define B_ROWS 8192
#define DH     1024
#define KTOT   2048   // D_IN + D_H
#define BM     256    // gatecol tile
#define BN     256    // batch tile
#define BK     32
#define NT     (KTOT / BK)   // 64 K-tiles
#define NBUF   4

using short8 = __attribute__((ext_vector_type(8))) short;  // 8 bf16 (4 VGPRs)
using f32x4  = __attribute__((ext_vector_type(4))) float;  // MFMA accumulator

// f32 -> bf16 round-to-nearest-even
__device__ __forceinline__ short bfr(float f) {
    uint32_t u = __float_as_uint(f);
    u = (u + 0x7FFFu + ((u >> 16) & 1u)) >> 16;
    return (short)u;
}

__device__ __forceinline__ float sigm(float x) {
    x = fminf(fmaxf(x, -20.f), 20.f);
    return 1.f / (1.f + __expf(-x));
}
__device__ __forceinline__ float tanh_(float x) {
    x = fminf(fmaxf(x, -10.f), 10.f);
    float e = __expf(2.f * x);
    return (e - 1.f) / (e + 1.f);
}

// async global->LDS, 16B per lane (HW: wave-uniform LDS base + lane*16)
__device__ __forceinline__ void gl16(const void* g, void* l) {
    __builtin_amdgcn_global_load_lds(
        (const __attribute__((address_space(1))) uint32_t*)(uintptr_t)g,
        (__attribute__((address_space(3))) uint32_t*)(uint32_t)(uintptr_t)l,
        16, 0, 0);
}

// A[8192][2048] bf16 = [x | h]   (batch-major, K contiguous)
__global__ __launch_bounds__(256) void build_A(const float* __restrict__ x,
                                               const float* __restrict__ h,
                                               short* __restrict__ A) {
    int t   = blockIdx.x * 256 + threadIdx.x;
    int row = t >> 8;
    int col = (t & 255) * 8;
    const float* src = (col < 1024) ? (x + (size_t)row * 1024 + col)
                                    : (h + (size_t)row * 1024 + (col - 1024));
    float4 f0 = ((const float4*)src)[0];
    float4 f1 = ((const float4*)src)[1];
    short8 o;
    o[0] = bfr(f0.x); o[1] = bfr(f0.y); o[2] = bfr(f0.z); o[3] = bfr(f0.w);
    o[4] = bfr(f1.x); o[5] = bfr(f1.y); o[6] = bfr(f1.z); o[7] = bfr(f1.w);
    *(short8*)(A + (size_t)row * KTOT + col) = o;
}

// Wrow[4096][2048] bf16, GATE-INTERLEAVED rows: row r = 4*hcol + gate,
// gate order {i,f,o,c}:  Wrow[r] = [Wg[hcol] | Ug[hcol]]
__global__ __launch_bounds__(256) void build_W(
        const float* __restrict__ Wi, const float* __restrict__ Ui,
        const float* __restrict__ Wf, const float* __restrict__ Uf,
        const float* __restrict__ Wo, const float* __restrict__ Uo,
        const float* __restrict__ Wc, const float* __restrict__ Uc,
        short* __restrict__ Wrow) {
    int row  = blockIdx.x;
    int col  = threadIdx.x * 8;
    int n    = row >> 2;
    int gate = row & 3;
    const float* Wg = (gate == 0) ? Wi : (gate == 1) ? Wf : (gate == 2) ? Wo : Wc;
    const float* Ug = (gate == 0) ? Ui : (gate == 1) ? Uf : (gate == 2) ? Uo : Uc;
    const float* src = (col < 1024) ? (Wg + (size_t)n * 1024 + col)
                                    : (Ug + (size_t)n * 1024 + (col - 1024));
    float4 f0 = ((const float4*)src)[0];
    float4 f1 = ((const float4*)src)[1];
    short8 o;
    o[0] = bfr(f0.x); o[1] = bfr(f0.y); o[2] = bfr(f0.z); o[3] = bfr(f0.w);
    o[4] = bfr(f1.x); o[5] = bfr(f1.y); o[6] = bfr(f1.z); o[7] = bfr(f1.w);
    *(short8*)(Wrow + (size_t)row * KTOT + col) = o;
}

// gatesT = Wrow (M=4096) x A^T (N=8192), K=2048. 256x256 tile, 8 waves
// (2M x 4N), per-wave 128x64 output. 4-deep LDS ring, counted vmcnt(8):
// tile t+3 staged during tile t; loads stay in flight across barriers.
// LDS 16B-column XOR swizzle (k16 ^= (row>>1)&3) applied on global src
// (linear LDS dest, rule #21) and on ds_read -> ~conflict-free b128 reads.
__global__ __launch_bounds__(512, 2) void lstm_main(
        const short* __restrict__ Amat, const short* __restrict__ Wrow,
        const float* __restrict__ bi, const float* __restrict__ bff,
        const float* __restrict__ bo, const float* __restrict__ bc,
        const float* __restrict__ cin, float* __restrict__ out) {
    __shared__ __align__(16) short Wt[NBUF][BM * BK];   // 4 x 16 KB
    __shared__ __align__(16) short At[NBUF][BN * BK];   // 4 x 16 KB

    const int tid  = threadIdx.x;
    const int lane = tid & 63;
    const int wid  = tid >> 6;
    const int wr   = wid >> 2;          // 0..1  (M half)
    const int wc   = wid & 3;           // 0..3  (N quarter)
    const int l15  = lane & 15, l16 = lane >> 4;

    // XCD swizzle (512 % 8 == 0), mtile-major: per-XCD W panel ~2 MB (L2-fit)
    const int bid   = blockIdx.x;
    const int swz   = (bid & 7) * 64 + (bid >> 3);
    const int mtile = swz >> 5;         // 0..15
    const int ntile = swz & 31;         // 0..31
    const int m0 = mtile * BM;
    const int n0 = ntile * BN;

    // ---- staging addresses (global pre-swizzled, LDS linear) ----
    const int r0 = tid >> 2;                               // rows 0..127 (j=0), +128 (j=1)
    const int kk = (((tid & 3) ^ ((r0 >> 1) & 3))) * 8;    // swizzled 16B column
    const short* pw0 = Wrow + (size_t)(m0 + r0) * KTOT + kk;
    const short* pw1 = Wrow + (size_t)(m0 + r0 + 128) * KTOT + kk;
    const short* pa0 = Amat + (size_t)(n0 + r0) * KTOT + kk;
    const short* pa1 = Amat + (size_t)(n0 + r0 + 128) * KTOT + kk;

    auto stage = [&](int tt) {
        const int bb = tt & (NBUF - 1);
        short* lw = &Wt[bb][tid * 8];
        short* la = &At[bb][tid * 8];
        gl16(pw0, lw);
        gl16(pw1, lw + 4096);
        gl16(pa0, la);
        gl16(pa1, la + 4096);
        pw0 += BK; pw1 += BK; pa0 += BK; pa1 += BK;
    };

    // ---- fragment LDS offsets (shorts), same XOR on the read side ----
    const int koff  = (l16 ^ ((l15 >> 1) & 3)) * 8;
    const int wbase = (wr * 128 + l15) * BK + koff;
    const int abase = (wc * 64 + l15) * BK + koff;

    f32x4 acc[8][4];
    #pragma unroll
    for (int mi = 0; mi < 8; ++mi)
        #pragma unroll
        for (int ni = 0; ni < 4; ++ni)
            acc[mi][ni] = f32x4{0.f, 0.f, 0.f, 0.f};

    stage(0); stage(1); stage(2);

    #pragma unroll 4
    for (int t = 0; t < NT; ++t) {
        if (t < NT - 2) {
            asm volatile("s_waitcnt vmcnt(8)\n\ts_barrier" ::: "memory");
        } else if (t == NT - 2) {
            asm volatile("s_waitcnt vmcnt(4)\n\ts_barrier" ::: "memory");
        } else {
            asm volatile("s_waitcnt vmcnt(0)\n\ts_barrier" ::: "memory");
        }
        if (t + 3 < NT) stage(t + 3);

        const int bb = t & (NBUF - 1);
        const short* WB = &Wt[bb][0];
        const short* AB = &At[bb][0];

        short8 wf[4], af4[4], wg[4];
        #pragma unroll
        for (int mi = 0; mi < 4; ++mi)
            wf[mi] = *(const short8*)(WB + wbase + mi * 16 * BK);
        #pragma unroll
        for (int ni = 0; ni < 4; ++ni)
            af4[ni] = *(const short8*)(AB + abase + ni * 16 * BK);

        __builtin_amdgcn_s_setprio(1);
        #pragma unroll
        for (int mi = 0; mi < 4; ++mi)
            #pragma unroll
            for (int ni = 0; ni < 4; ++ni)
                acc[mi][ni] = __builtin_amdgcn_mfma_f32_16x16x32_bf16(
                    wf[mi], af4[ni], acc[mi][ni], 0, 0, 0);
        __builtin_amdgcn_s_setprio(0);

        #pragma unroll
        for (int mi = 0; mi < 4; ++mi)
            wg[mi] = *(const short8*)(WB + wbase + (64 + mi * 16) * BK);

        __builtin_amdgcn_s_setprio(1);
        #pragma unroll
        for (int mi = 0; mi < 4; ++mi)
            #pragma unroll
            for (int ni = 0; ni < 4; ++ni)
                acc[mi + 4][ni] = __builtin_amdgcn_mfma_f32_16x16x32_bf16(
                    wg[mi], af4[ni], acc[mi + 4][ni], 0, 0, 0);
        __builtin_amdgcn_s_setprio(0);
    }

    // epilogue: reg r = gate r of (hcol, batchrow); all lane-local
    const int hbase = (m0 >> 2) + wr * 32;
    #pragma unroll
    for (int mi = 0; mi < 8; ++mi) {
        const int hcol = hbase + mi * 4 + l16;
        const float bvi = bi[hcol];
        const float bvf = bff[hcol];
        const float bvo = bo[hcol];
        const float bvc = bc[hcol];
        #pragma unroll
        for (int ni = 0; ni < 4; ++ni) {
            const size_t brow = (size_t)(n0 + wc * 64 + ni * 16 + l15);
            const float cv = cin[brow * DH + hcol];
            const float gi = acc[mi][ni][0] + bvi;
            const float gf = acc[mi][ni][1] + bvf;
            const float go = acc[mi][ni][2] + bvo;
            const float gc = acc[mi][ni][3] + bvc;
            const float nc = sigm(gf) * cv + sigm(gi) * tanh_(gc);
            const float nh = sigm(go) * tanh_(nc);
            out[brow * DH + hcol] = nh;
            out[(size_t)B_ROWS * DH + brow * DH + hcol] = nc;
        }
    }
}

extern "C" void kernel_launch(void* const* d_in, const int* in_sizes, int n_in,
                              void* d_out, int out_size, void* d_ws, size_t ws_size,
                              hipStream_t stream) {
    (void)in_sizes; (void)n_in; (void)out_size; (void)ws_size;
    const float* x  = (const float*)d_in[0];
    const float* h  = (const float*)d_in[1];
    const float* c  = (const float*)d_in[2];
    const float* Wi = (const float*)d_in[3];
    const float* bi = (const float*)d_in[4];
    const float* Ui = (const float*)d_in[5];
    const float* Wf = (const float*)d_in[6];
    const float* bf = (const float*)d_in[7];
    const float* Uf = (const float*)d_in[8];
    const float* Wo = (const float*)d_in[9];
    const float* bo = (const float*)d_in[10];
    const float* Uo = (const float*)d_in[11];
    const float* Wc = (const float*)d_in[12];
    const float* bc = (const float*)d_in[13];
    const float* Uc = (const float*)d_in[14];
    float* out = (float*)d_out;

    short* A    = (short*)d_ws;                              // 32 MiB
    short* Wrow = A + (size_t)B_ROWS * KTOT;                 // +16 MiB

    hipLaunchKernelGGL(build_A, dim3(8192), dim3(256), 0, stream, x, h, A);
    hipLaunchKernelGGL(build_W, dim3(4096), dim3(256), 0, stream,
                       Wi, Ui, Wf, Uf, Wo, Uo, Wc, Uc, Wrow);
    hipLaunchKernelGGL(lstm_main, dim3(512), dim3(512), 0, stream,
                       A, Wrow, bi, bf, bo, bc, c, out);
}